// Round 6
// baseline (147.306 us; speedup 1.0000x reference)
//
#include <hip/hip_runtime.h>

#define N_NODES 8192
#define DIM     128
#define N_COMM  100
#define MARGIN  1.0f

// pos kernel LDS tiling (unchanged from R4/R5, measured conflict-free)
#define LDS_STRP 72

typedef __attribute__((ext_vector_type(8)))  short bf16x8;
typedef __attribute__((ext_vector_type(16))) float f32x16;

__device__ inline unsigned short f32_to_bf16_rne(float f) {
    unsigned u = __float_as_uint(f);
    unsigned r = u + 0x7fffu + ((u >> 16) & 1u);
    return (unsigned short)(r >> 16);
}
__device__ inline float bf16_to_f32(unsigned short h) {
    return __uint_as_float(((unsigned)h) << 16);
}

// ---------------------------------------------------------------------------
// Kernel 0 (merged): blocks 0..2047 = bf16 hi/lo split + row sq norms + min_d2
// init (wave per row); block 2048 = community bucketing.
__global__ __launch_bounds__(256)
void prep_kernel(const float* __restrict__ x,
                 const int* __restrict__ comm,
                 unsigned short* __restrict__ xhi,
                 unsigned short* __restrict__ xlo,
                 float* __restrict__ sq,
                 unsigned int* __restrict__ min_d2,
                 int* __restrict__ offs,
                 int* __restrict__ members) {
    __shared__ int scnt[N_COMM];
    __shared__ int scur[N_COMM];
    const int tid = threadIdx.x;

    if (blockIdx.x < 2048) {
        int row  = blockIdx.x * 4 + (tid >> 6);
        int lane = tid & 63;
        const float* p = x + (size_t)row * DIM;
        float v0 = p[lane], v1 = p[lane + 64];
        unsigned short h0 = f32_to_bf16_rne(v0), h1 = f32_to_bf16_rne(v1);
        unsigned short l0 = f32_to_bf16_rne(v0 - bf16_to_f32(h0));
        unsigned short l1 = f32_to_bf16_rne(v1 - bf16_to_f32(h1));
        size_t base = (size_t)row * DIM;
        xhi[base + lane] = h0;  xhi[base + 64 + lane] = h1;
        xlo[base + lane] = l0;  xlo[base + 64 + lane] = l1;
        float s = v0 * v0 + v1 * v1;
        #pragma unroll
        for (int off = 32; off > 0; off >>= 1) s += __shfl_down(s, off);
        if (lane == 0) {
            sq[row] = s;
            min_d2[row] = 0x7f800000u;   // +inf bits
        }
        return;
    }

    // ---- bucketing block
    if (tid < N_COMM) scnt[tid] = 0;
    __syncthreads();
    for (int i = tid; i < N_NODES; i += 256) atomicAdd(&scnt[comm[i]], 1);
    __syncthreads();
    if (tid == 0) {
        int acc = 0;
        for (int c = 0; c < N_COMM; ++c) { scur[c] = acc; offs[c] = acc; acc += scnt[c]; }
        offs[N_COMM] = acc;
    }
    __syncthreads();
    for (int i = tid; i < N_NODES; i += 256) {
        int p = atomicAdd(&scur[comm[i]], 1);
        members[p] = i;
    }
}

// ---------------------------------------------------------------------------
// Kernel 1 (v3): MFMA X·X^T (bf16 hi/lo), exact triangular grid, FRAGMENT-
// PACKED LDS: each MFMA operand (32 rows x 16 k, one wave's A or B fragment)
// is a contiguous 1 KB block laid out lane-major (lane*16 B). Consequences:
//  - ds_read_b128 is lane-sequential -> structurally conflict-free, no padding
//  - staging matches global_load_lds's wave-uniform-base+lane*16 contract ->
//    async DMA, no VGPR round-trip, no ds_write, no staging VALU
// LDS: 4 tiles(Ahi,Alo,Bhi,Blo) x 4 rowgroups x 2 kchunks x 64 lanes x 16 B
//    = 32 KB (+1 KB epilogue overlay slack, + colmin).
// C/D layout (m74/m101): col = lane&31, row = (reg&3) + 8*(reg>>2) + 4*(lane>>5).
// A/B layout: m(n) = lane&31, k = (lane>>5)*8 + j, 8 contiguous bf16.
__global__ __launch_bounds__(256, 3)
void minneg_mfma_kernel(const unsigned short* __restrict__ xhi,
                        const unsigned short* __restrict__ xlo,
                        const int* __restrict__ comm,
                        const float* __restrict__ sq,
                        unsigned int* __restrict__ min_d2) {
    __shared__ __align__(16) char smem[33792];
    __shared__ unsigned int colmin[128];
    unsigned short (*frag)[4][2][64][8] =
        (unsigned short (*)[4][2][64][8])smem;     // [tile][rg][kc][lane][8]
    float (*rowpart)[66] = (float (*)[66])smem;    // epilogue overlay, 33792 B

    // linear -> lower-triangle (bx >= by)
    const int b = blockIdx.x;
    int bx = (int)((sqrtf(8.f * (float)b + 1.f) - 1.f) * 0.5f);
    while ((bx + 1) * (bx + 2) / 2 <= b) ++bx;
    while (bx * (bx + 1) / 2 > b) --bx;
    const int by = b - bx * (bx + 1) / 2;

    const int tid  = threadIdx.x;
    const int lane = tid & 63;
    const int w    = tid >> 6;
    const int wr   = w >> 1, wc = w & 1;
    const int lr   = lane & 31;
    const int lh   = lane >> 5;
    const int i0   = bx * 128;      // A rows
    const int j0   = by * 128;      // B rows (= output cols)

    if (tid < 128) colmin[tid] = 0x7f800000u;

    // this wave stages tile w: 0=Ahi 1=Alo 2=Bhi 3=Blo.
    // lane l fetches row (rbase + rg*32 + (l&31)), k-chunk [(l>>5)*8 .. +8)
    const unsigned short* src   = (w & 1) ? xlo : xhi;
    const int             rbw   = ((w & 2) ? j0 : i0) + lr;
    const unsigned short* gbase = src + (size_t)rbw * DIM + lh * 8;

    f32x16 acc[2][2];
    #pragma unroll
    for (int g = 0; g < 2; ++g)
        #pragma unroll
        for (int h = 0; h < 2; ++h)
            #pragma unroll
            for (int e = 0; e < 16; ++e) acc[g][h][e] = 0.f;

    for (int kq = 0; kq < 4; ++kq) {      // K in 32-wide quarters
        __syncthreads();                  // previous kq's fragment reads done
        #pragma unroll
        for (int rg = 0; rg < 4; ++rg)
            #pragma unroll
            for (int kc = 0; kc < 2; ++kc) {
                const unsigned short* g = gbase + kq * 32 + rg * 32 * DIM + kc * 16;
                __builtin_amdgcn_global_load_lds(
                    (const __attribute__((address_space(1))) void*)g,
                    (__attribute__((address_space(3))) void*)&frag[w][rg][kc][0][0],
                    16, 0, 0);
            }
        __syncthreads();                  // DMA drained (vmcnt) + all tiles staged

        #pragma unroll
        for (int kc = 0; kc < 2; ++kc) {
            bf16x8 ahi[2], bhi[2];
            #pragma unroll
            for (int g = 0; g < 2; ++g)
                ahi[g] = *(const bf16x8*)&frag[0][wr * 2 + g][kc][lane][0];
            #pragma unroll
            for (int h = 0; h < 2; ++h)
                bhi[h] = *(const bf16x8*)&frag[2][wc * 2 + h][kc][lane][0];
            #pragma unroll
            for (int g = 0; g < 2; ++g)
                #pragma unroll
                for (int h = 0; h < 2; ++h)
                    acc[g][h] = __builtin_amdgcn_mfma_f32_32x32x16_bf16(
                        ahi[g], bhi[h], acc[g][h], 0, 0, 0);
            {
                bf16x8 alo[2];
                #pragma unroll
                for (int g = 0; g < 2; ++g)
                    alo[g] = *(const bf16x8*)&frag[1][wr * 2 + g][kc][lane][0];
                #pragma unroll
                for (int g = 0; g < 2; ++g)
                    #pragma unroll
                    for (int h = 0; h < 2; ++h)
                        acc[g][h] = __builtin_amdgcn_mfma_f32_32x32x16_bf16(
                            alo[g], bhi[h], acc[g][h], 0, 0, 0);
            }
            {
                bf16x8 blo[2];
                #pragma unroll
                for (int h = 0; h < 2; ++h)
                    blo[h] = *(const bf16x8*)&frag[3][wc * 2 + h][kc][lane][0];
                #pragma unroll
                for (int g = 0; g < 2; ++g)
                    #pragma unroll
                    for (int h = 0; h < 2; ++h)
                        acc[g][h] = __builtin_amdgcn_mfma_f32_32x32x16_bf16(
                            ahi[g], blo[h], acc[g][h], 0, 0, 0);
            }
        }
    }

    // ---- epilogue: d2 = sq_i + sq_j - 2*dot ; col-min AND row-min over negatives
    int   civ[2][4][4];
    float sqv[2][4][4];
    #pragma unroll
    for (int g = 0; g < 2; ++g)
        #pragma unroll
        for (int q = 0; q < 4; ++q) {
            int rb = i0 + wr * 64 + g * 32 + 4 * lh + 8 * q;
            *(int4*)&civ[g][q][0]   = *(const int4*)&comm[rb];
            *(float4*)&sqv[g][q][0] = *(const float4*)&sq[rb];
        }

    const float FINF = __uint_as_float(0x7f800000u);
    float rmin[2][16];
    #pragma unroll
    for (int g = 0; g < 2; ++g)
        #pragma unroll
        for (int e = 0; e < 16; ++e) rmin[g][e] = FINF;

    #pragma unroll
    for (int h = 0; h < 2; ++h) {
        int colt = wc * 64 + h * 32 + lr;
        int j  = j0 + colt;
        int cj = comm[j];
        float sqj = sq[j];
        float cmin = FINF;
        #pragma unroll
        for (int g = 0; g < 2; ++g)
            #pragma unroll
            for (int q = 0; q < 4; ++q)
                #pragma unroll
                for (int t = 0; t < 4; ++t) {
                    float d2 = fmaxf(sqv[g][q][t] + sqj - 2.f * acc[g][h][q * 4 + t], 0.f);
                    if (civ[g][q][t] != cj) {
                        cmin = fminf(cmin, d2);
                        rmin[g][q * 4 + t] = fminf(rmin[g][q * 4 + t], d2);
                    }
                }
        cmin = fminf(cmin, __shfl_xor(cmin, 32));
        if (lh == 0) atomicMin(&colmin[colt], __float_as_uint(cmin));
    }

    // row-min: scatter per-thread partials into LDS overlay, then 128-thread reduce
    __syncthreads();                           // all fragment reads of frag done
    #pragma unroll
    for (int g = 0; g < 2; ++g)
        #pragma unroll
        for (int q = 0; q < 4; ++q)
            #pragma unroll
            for (int t = 0; t < 4; ++t) {
                int rowl = wr * 64 + g * 32 + 4 * lh + 8 * q + t;
                rowpart[rowl][wc * 32 + lr] = rmin[g][q * 4 + t];
            }
    __syncthreads();
    if (tid < 128) {
        float m = FINF;
        #pragma unroll
        for (int k = 0; k < 16; ++k) {
            float4 v = *(const float4*)&rowpart[tid][k * 4];
            m = fminf(m, fminf(fminf(v.x, v.y), fminf(v.z, v.w)));
        }
        atomicMin(&min_d2[i0 + tid], __float_as_uint(m));
        atomicMin(&min_d2[j0 + tid], colmin[tid]);
    }
}

// ---------------------------------------------------------------------------
// Kernel 2: positives via community-gathered MFMA Gram, one block/community,
// wave-uniform subtile guards. (unchanged from R5 — conflict-free stride 72)
__global__ __launch_bounds__(256, 2)
void pos_mfma_kernel(const unsigned short* __restrict__ xhi,
                     const unsigned short* __restrict__ xlo,
                     const float* __restrict__ sq,
                     const unsigned int* __restrict__ min_d2,
                     const int* __restrict__ offs,
                     const int* __restrict__ members,
                     double* __restrict__ psum,
                     unsigned int* __restrict__ pcnt) {
    __shared__ __align__(16) unsigned short lds[4][128][LDS_STRP];  // 72 KB
    __shared__ float sqA[128], sqB[128], mnA[128];
    __shared__ double sred[4];
    __shared__ unsigned int cred[4];

    const int tid  = threadIdx.x;
    const int lane = tid & 63;
    const int w    = tid >> 6;
    const int wr   = w >> 1, wc = w & 1;
    const int lr   = lane & 31;
    const int lh   = lane >> 5;

    const int c    = blockIdx.x;
    const int beg  = offs[c], end = offs[c + 1];
    const int size = end - beg;
    const int nt   = (size + 127) >> 7;

    float tsum = 0.f;
    unsigned int tcnt = 0u;

    for (int tr = 0; tr < nt; ++tr)
    for (int tc = 0; tc < nt; ++tc) {
        bool av[2], bv[2];
        #pragma unroll
        for (int g = 0; g < 2; ++g) av[g] = (tr * 128 + wr * 64 + g * 32) < size;
        #pragma unroll
        for (int h = 0; h < 2; ++h) bv[h] = (tc * 128 + wc * 64 + h * 32) < size;

        __syncthreads();
        if (tid < 128) {
            int ii = beg + tr * 128 + tid;
            if (ii < end) {
                int ia = members[ii];
                sqA[tid] = sq[ia];
                unsigned int mb = min_d2[ia];
                mnA[tid] = (mb == 0x7f800000u) ? -1.f
                         : sqrtf(fmaxf(__uint_as_float(mb), 0.f));
            } else { sqA[tid] = 0.f; mnA[tid] = -1.f; }
        } else {
            int t2 = tid - 128;
            int jj = beg + tc * 128 + t2;
            sqB[t2] = (jj < end) ? sq[members[jj]] : 0.f;
        }

        f32x16 acc[2][2];
        #pragma unroll
        for (int g = 0; g < 2; ++g)
            #pragma unroll
            for (int h = 0; h < 2; ++h)
                #pragma unroll
                for (int e = 0; e < 16; ++e) acc[g][h][e] = 0.f;

        for (int kh = 0; kh < 2; ++kh) {
            __syncthreads();
            #pragma unroll
            for (int it = 0; it < 16; ++it) {
                int g    = tid + it * 256;
                int tile = g >> 10;
                int row  = (g >> 3) & 127;
                int seg  = g & 7;
                int mi   = beg + ((tile & 2) ? tc : tr) * 128 + row;
                int node = (mi < end) ? members[mi] : 0;
                const unsigned short* src = (tile & 1) ? xlo : xhi;
                uint4 v = *(const uint4*)&src[(size_t)node * DIM + kh * 64 + seg * 8];
                *(uint4*)&lds[tile][row][seg * 8] = v;
            }
            __syncthreads();

            #pragma unroll
            for (int ks = 0; ks < 4; ++ks) {
                const int kb = ks * 16 + lh * 8;
                bf16x8 ahi[2], alo[2], bhi[2], blo[2];
                #pragma unroll
                for (int g = 0; g < 2; ++g) if (av[g]) {
                    ahi[g] = *(const bf16x8*)&lds[0][wr * 64 + g * 32 + lr][kb];
                    alo[g] = *(const bf16x8*)&lds[1][wr * 64 + g * 32 + lr][kb];
                }
                #pragma unroll
                for (int h = 0; h < 2; ++h) if (bv[h]) {
                    bhi[h] = *(const bf16x8*)&lds[2][wc * 64 + h * 32 + lr][kb];
                    blo[h] = *(const bf16x8*)&lds[3][wc * 64 + h * 32 + lr][kb];
                }
                #pragma unroll
                for (int g = 0; g < 2; ++g)
                    #pragma unroll
                    for (int h = 0; h < 2; ++h) if (av[g] && bv[h]) {
                        acc[g][h] = __builtin_amdgcn_mfma_f32_32x32x16_bf16(
                            ahi[g], bhi[h], acc[g][h], 0, 0, 0);
                        acc[g][h] = __builtin_amdgcn_mfma_f32_32x32x16_bf16(
                            ahi[g], blo[h], acc[g][h], 0, 0, 0);
                        acc[g][h] = __builtin_amdgcn_mfma_f32_32x32x16_bf16(
                            alo[g], bhi[h], acc[g][h], 0, 0, 0);
                    }
            }
        }

        #pragma unroll
        for (int h = 0; h < 2; ++h) {
            if (!bv[h]) continue;
            int coll = wc * 64 + h * 32 + lr;
            int jv   = tc * 128 + coll;
            float sqj = sqB[coll];
            #pragma unroll
            for (int g = 0; g < 2; ++g) {
                if (!av[g]) continue;
                #pragma unroll
                for (int q = 0; q < 4; ++q)
                    #pragma unroll
                    for (int t = 0; t < 4; ++t) {
                        int rowl = wr * 64 + g * 32 + 4 * lh + 8 * q + t;
                        int iv   = tr * 128 + rowl;
                        float mn = mnA[rowl];
                        if (iv < size && jv < size && iv != jv && mn >= 0.f) {
                            float d2 = sqA[rowl] + sqj - 2.f * acc[g][h][q * 4 + t];
                            float dist = sqrtf(fmaxf(d2, 0.f));
                            tsum += fmaxf(dist - mn + MARGIN, 0.f);
                            tcnt += 1u;
                        }
                    }
            }
        }
    }

    #pragma unroll
    for (int off = 32; off > 0; off >>= 1) {
        tsum += __shfl_down(tsum, off);
        tcnt += __shfl_down(tcnt, off);
    }
    if (lane == 0) { sred[w] = (double)tsum; cred[w] = tcnt; }
    __syncthreads();
    if (tid == 0) {
        psum[c] = sred[0] + sred[1] + sred[2] + sred[3];
        pcnt[c] = cred[0] + cred[1] + cred[2] + cred[3];
    }
}

// ---------------------------------------------------------------------------
// Kernel 3: reduce 100 community partials -> final mean.
__global__ __launch_bounds__(256)
void finalize_kernel(const double* __restrict__ psum,
                     const unsigned int* __restrict__ pcnt,
                     float* __restrict__ out) {
    __shared__ double       ds[256];
    __shared__ unsigned int cs[256];
    const int t = threadIdx.x;
    double s = 0.0; unsigned int c = 0u;
    for (int b = t; b < N_COMM; b += 256) { s += psum[b]; c += pcnt[b]; }
    ds[t] = s; cs[t] = c;
    __syncthreads();
    for (int off = 128; off > 0; off >>= 1) {
        if (t < off) { ds[t] += ds[t + off]; cs[t] += cs[t + off]; }
        __syncthreads();
    }
    if (t == 0) out[0] = (cs[0] > 0u) ? (float)(ds[0] / (double)cs[0]) : 0.f;
}

// ---------------------------------------------------------------------------
extern "C" void kernel_launch(void* const* d_in, const int* in_sizes, int n_in,
                              void* d_out, int out_size, void* d_ws, size_t ws_size,
                              hipStream_t stream) {
    const float* x    = (const float*)d_in[0];
    const int*   comm = (const int*)d_in[1];
    float*       out  = (float*)d_out;

    // workspace layout (bytes):
    //       0 float  sq[8192]           32768
    //   32768 uint   min_d2[8192]       32768
    //   65536 int    offs[101]            512 (padded)
    //   66048 int    members[8192]      32768
    //   98816 double psum[100]           1024 (padded)
    //   99840 uint   pcnt[100]            512 (padded)
    //  100352 ushort xhi[8192*128]    2097152
    // 2197504 ushort xlo[8192*128]    2097152   (total ~4.1 MB)
    char* ws = (char*)d_ws;
    float*          sq      = (float*)(ws);
    unsigned int*   min_d2  = (unsigned int*)(ws + 32768);
    int*            offs    = (int*)(ws + 65536);
    int*            members = (int*)(ws + 66048);
    double*         psum    = (double*)(ws + 98816);
    unsigned int*   pcnt    = (unsigned int*)(ws + 99840);
    unsigned short* xhi     = (unsigned short*)(ws + 100352);
    unsigned short* xlo     = (unsigned short*)(ws + 2197504);

    prep_kernel<<<2049, 256, 0, stream>>>(x, comm, xhi, xlo, sq, min_d2,
                                          offs, members);

    const int ntri = (N_NODES / 128) * (N_NODES / 128 + 1) / 2;   // 2080
    minneg_mfma_kernel<<<ntri, 256, 0, stream>>>(xhi, xlo, comm, sq, min_d2);

    pos_mfma_kernel<<<N_COMM, 256, 0, stream>>>(xhi, xlo, sq, min_d2, offs, members,
                                                psum, pcnt);

    finalize_kernel<<<1, 256, 0, stream>>>(psum, pcnt, out);
}